// Round 1
// baseline (680.193 us; speedup 1.0000x reference)
//
#include <hip/hip_runtime.h>
#include <hip/hip_bf16.h>

// Matryoshka linear: y[m][n] = sum_k x[m][k] * W_seg[n_local][k]
//   seg0: n in [0,1024),    K=1024, W0 [1024][1024]
//   seg1: n in [1024,2048), K=2048, W1 [1024][2048]
//   seg2: n in [2048,4096), K=4096, W2 [2048][4096]
// M = 4*4096 = 16384, out is [16384][4096] fp32.
//
// Strategy: convert x and W to bf16 in d_ws (x_bf16 = 134MB -> L3-resident),
// then one fused MFMA GEMM over all 3 segments (m97 128x128 structure).

typedef short bf16x8 __attribute__((ext_vector_type(8)));
typedef float f32x4 __attribute__((ext_vector_type(4)));

__device__ __forceinline__ ushort f2bf(float f) {
  union { float f; unsigned u; } c; c.f = f;
  unsigned u = c.u;
  unsigned r = u + 0x7fffu + ((u >> 16) & 1u);  // round-to-nearest-even
  return (ushort)(r >> 16);
}

__global__ void cvt_f32_bf16(const float* __restrict__ in,
                             ushort* __restrict__ out, int n4) {
  int i = blockIdx.x * blockDim.x + threadIdx.x;
  int stride = gridDim.x * blockDim.x;
  const float4* in4 = (const float4*)in;
  ushort4* out4 = (ushort4*)out;
  for (int j = i; j < n4; j += stride) {
    float4 v = in4[j];
    ushort4 o;
    o.x = f2bf(v.x); o.y = f2bf(v.y); o.z = f2bf(v.z); o.w = f2bf(v.w);
    out4[j] = o;
  }
}

#define BM 128
#define BN 128
#define BK 32

__device__ __forceinline__ void gload_lds16(const ushort* g, ushort* l) {
  // async global->LDS, 16B per lane; LDS dest is wave-uniform base + lane*16
  __builtin_amdgcn_global_load_lds(
      (const __attribute__((address_space(1))) void*)g,
      (__attribute__((address_space(3))) void*)l, 16, 0, 0);
}

__global__ __launch_bounds__(256, 2) void matry_gemm(
    const ushort* __restrict__ xbf,   // [16384][4096] bf16
    const ushort* __restrict__ w0,    // [1024][1024]
    const ushort* __restrict__ w1,    // [1024][2048]
    const ushort* __restrict__ w2,    // [2048][4096]
    float* __restrict__ out) {        // [16384][4096] f32
  __shared__ __align__(16) ushort sA[BM * BK];
  __shared__ __align__(16) ushort sB[BN * BK];

  const int bx = blockIdx.x;
  const int ct = bx & 31;   // col tile 0..31 (fastest -> A-panel reuse in L2/L3)
  const int rt = bx >> 5;   // row tile 0..127

  int K; const ushort* W; int nlt;
  if (ct < 8)       { K = 1024; W = w0; nlt = ct; }
  else if (ct < 16) { K = 2048; W = w1; nlt = ct - 8; }
  else              { K = 4096; W = w2; nlt = ct - 16; }

  const int m0 = rt * BM;
  const int nloc0 = nlt * BN;   // row offset inside W_seg
  const int nglob0 = ct * BN;   // column offset in out

  const int t = threadIdx.x;
  const int wid = t >> 6;
  const int lane = t & 63;
  const int wr = wid >> 1, wc = wid & 1;   // 2x2 waves, 64x64 each

  f32x4 acc[4][4];
#pragma unroll
  for (int mi = 0; mi < 4; ++mi)
#pragma unroll
    for (int ni = 0; ni < 4; ++ni)
      acc[mi][ni] = (f32x4){0.f, 0.f, 0.f, 0.f};

  const ushort* Abase = xbf + (long)m0 * 4096;
  const ushort* Bbase = W + (long)nloc0 * K;

  const int fr = lane & 15;          // fragment row (A) / W row (B)
  const int kq = (lane >> 4) * 8;    // k offset within BK

  for (int kt = 0; kt < K; kt += BK) {
    __syncthreads();   // prior ds_reads done before overwrite
    // stage A tile 128x32 bf16 = 8KB: 2 issues of 256 lanes x 16B
#pragma unroll
    for (int i = 0; i < 2; ++i) {
      int off = i * 2048 + t * 8;          // element offset in tile
      int row = off >> 5, col = off & 31;  // 4 threads per 64B row
      gload_lds16(Abase + (long)row * 4096 + kt + col, &sA[off]);
    }
#pragma unroll
    for (int i = 0; i < 2; ++i) {
      int off = i * 2048 + t * 8;
      int row = off >> 5, col = off & 31;
      gload_lds16(Bbase + (long)row * K + kt + col, &sB[off]);
    }
    __syncthreads();   // vmcnt(0) drain + barrier (m97 structure)

    bf16x8 af[4], bfr[4];
#pragma unroll
    for (int mi = 0; mi < 4; ++mi)
      af[mi] = *(const bf16x8*)&sA[(wr * 64 + mi * 16 + fr) * BK + kq];
#pragma unroll
    for (int ni = 0; ni < 4; ++ni)
      bfr[ni] = *(const bf16x8*)&sB[(wc * 64 + ni * 16 + fr) * BK + kq];
#pragma unroll
    for (int mi = 0; mi < 4; ++mi)
#pragma unroll
      for (int ni = 0; ni < 4; ++ni)
        acc[mi][ni] = __builtin_amdgcn_mfma_f32_16x16x32_bf16(
            af[mi], bfr[ni], acc[mi][ni], 0, 0, 0);
  }

  // epilogue: C/D layout col=lane&15, row=(lane>>4)*4+reg  [m89]
  const int rq = (lane >> 4) * 4;
#pragma unroll
  for (int mi = 0; mi < 4; ++mi) {
#pragma unroll
    for (int ni = 0; ni < 4; ++ni) {
      int n = nglob0 + wc * 64 + ni * 16 + fr;
#pragma unroll
      for (int r = 0; r < 4; ++r) {
        int m = m0 + wr * 64 + mi * 16 + rq + r;
        out[(long)m * 4096 + n] = acc[mi][ni][r];
      }
    }
  }
}

// Correct-but-slow fallback if workspace is too small for bf16 copies.
__global__ void naive_kernel(const float* __restrict__ x,
                             const float* __restrict__ W0,
                             const float* __restrict__ W1,
                             const float* __restrict__ W2,
                             float* __restrict__ out) {
  long idx = (long)blockIdx.x * 256 + threadIdx.x;
  int n = (int)(idx & 4095);
  long m = idx >> 12;
  int K; const float* W; int nl;
  if (n < 1024)      { K = 1024; W = W0; nl = n; }
  else if (n < 2048) { K = 2048; W = W1; nl = n - 1024; }
  else               { K = 4096; W = W2; nl = n - 2048; }
  const float* xr = x + m * 4096;
  const float* wr = W + (long)nl * K;
  float s = 0.f;
  for (int k = 0; k < K; ++k) s += xr[k] * wr[k];
  out[idx] = s;
}

extern "C" void kernel_launch(void* const* d_in, const int* in_sizes, int n_in,
                              void* d_out, int out_size, void* d_ws,
                              size_t ws_size, hipStream_t stream) {
  const float* x  = (const float*)d_in[0];
  const float* W0 = (const float*)d_in[1];
  const float* W1 = (const float*)d_in[2];
  const float* W2 = (const float*)d_in[3];
  float* out = (float*)d_out;

  const size_t xN  = (size_t)16384 * 4096;   // 67,108,864
  const size_t w0N = (size_t)1024 * 1024;
  const size_t w1N = (size_t)1024 * 2048;
  const size_t w2N = (size_t)2048 * 4096;
  const size_t need = (xN + w0N + w1N + w2N) * sizeof(ushort);  // ~150 MB

  if (ws_size >= need) {
    ushort* xbf = (ushort*)d_ws;
    ushort* w0b = xbf + xN;
    ushort* w1b = w0b + w0N;
    ushort* w2b = w1b + w1N;
    cvt_f32_bf16<<<2048, 256, 0, stream>>>(x, xbf, (int)(xN >> 2));
    cvt_f32_bf16<<<256, 256, 0, stream>>>(W0, w0b, (int)(w0N >> 2));
    cvt_f32_bf16<<<256, 256, 0, stream>>>(W1, w1b, (int)(w1N >> 2));
    cvt_f32_bf16<<<512, 256, 0, stream>>>(W2, w2b, (int)(w2N >> 2));
    // grid: 128 row-tiles x 32 col-tiles
    matry_gemm<<<4096, 256, 0, stream>>>(xbf, w0b, w1b, w2b, out);
  } else {
    naive_kernel<<<(int)((xN + 255) / 256), 256, 0, stream>>>(x, W0, W1, W2, out);
  }
}

// Round 2
// 462.899 us; speedup vs baseline: 1.4694x; 1.4694x over previous
//
#include <hip/hip_runtime.h>
#include <hip/hip_bf16.h>

// Matryoshka linear: y[m][n] = sum_k x[m][k] * W_seg[n_local][k]
//   seg0: n in [0,1024),    K=1024, W0 [1024][1024]
//   seg1: n in [1024,2048), K=2048, W1 [1024][2048]
//   seg2: n in [2048,4096), K=4096, W2 [2048][4096]
// M = 16384, out [16384][4096] fp32.
//
// Round 2: 256x256 tile, BK=32, 8 waves (2x4), 4-buffer LDS rotation,
// prefetch distance 3, counted vmcnt(8), raw s_barrier, T2 XOR-swizzle
// (both-sides: pre-swizzled global source + swizzled ds_read), setprio.

typedef short bf16x8 __attribute__((ext_vector_type(8)));
typedef float f32x4 __attribute__((ext_vector_type(4)));

__device__ __forceinline__ ushort f2bf(float f) {
  union { float f; unsigned u; } c; c.f = f;
  unsigned u = c.u;
  unsigned r = u + 0x7fffu + ((u >> 16) & 1u);  // RNE
  return (ushort)(r >> 16);
}

__global__ void cvt_f32_bf16(const float* __restrict__ in,
                             ushort* __restrict__ out, int n4) {
  int i = blockIdx.x * blockDim.x + threadIdx.x;
  int stride = gridDim.x * blockDim.x;
  const float4* in4 = (const float4*)in;
  ushort4* out4 = (ushort4*)out;
  for (int j = i; j < n4; j += stride) {
    float4 v = in4[j];
    ushort4 o;
    o.x = f2bf(v.x); o.y = f2bf(v.y); o.z = f2bf(v.z); o.w = f2bf(v.w);
    out4[j] = o;
  }
}

__device__ __forceinline__ void gload16(const ushort* g, const ushort* l) {
  __builtin_amdgcn_global_load_lds(
      (const __attribute__((address_space(1))) void*)g,
      (__attribute__((address_space(3))) void*)l, 16, 0, 0);
}

#define TILE_E 8192   // one 256x32 bf16 tile = 16 KB = 8192 ushorts

#define MF(av, bv, mi, ni) \
  acc[mi][ni] = __builtin_amdgcn_mfma_f32_16x16x32_bf16(av, bv, acc[mi][ni], 0, 0, 0)

__global__ __launch_bounds__(512, 2) void matry_gemm(
    const ushort* __restrict__ xbf,   // [16384][4096] bf16
    const ushort* __restrict__ w0,    // [1024][1024]
    const ushort* __restrict__ w1,    // [1024][2048]
    const ushort* __restrict__ w2,    // [2048][4096]
    float* __restrict__ out) {        // [16384][4096] f32
  __shared__ __align__(16) ushort sA[4][TILE_E];
  __shared__ __align__(16) ushort sB[4][TILE_E];

  const int bid = blockIdx.x;
  const int rt = bid & 63;    // row tile fastest: balanced per-CU K mix,
  const int ct = bid >> 6;    // same-A-panel blocks share an XCD (64%8==0)

  int K; const ushort* W; int nl0;
  if (ct < 4)      { K = 1024; W = w0; nl0 = ct * 256; }
  else if (ct < 8) { K = 2048; W = w1; nl0 = (ct - 4) * 256; }
  else             { K = 4096; W = w2; nl0 = (ct - 8) * 256; }
  const int NT = K >> 5;          // K-tiles of 32 (>=32)
  const int m0 = rt * 256;
  const int n0 = ct * 256;

  const int tid  = threadIdx.x;
  const int wid  = tid >> 6;
  const int lane = tid & 63;
  const int wm = wid >> 2;        // 0..1  (row half)
  const int wn = wid & 3;         // 0..3  (col quarter)
  const int fr = lane & 15;
  // swizzled k-slot for ds_read: elements; XOR slot(lane>>4) with row&3
  const int swz_e = (((lane >> 4) ^ (lane & 3)) << 3);

  // ---- staging constants (pre-swizzled global source, linear LDS dest) ----
  // LDS byte p = issue*8192 + tid*16  ->  row = issue*128 + tid/4,
  // source col = ((tid&3) ^ (row&3)) * 8 elements
  const int srow = tid >> 2;                               // 0..127
  const int scol = (((tid & 3) ^ (srow & 3)) << 3);        // 0..24
  const ushort* Asrc0 = xbf + (size_t)(m0 + srow) * 4096 + scol;
  const ushort* Asrc1 = Asrc0 + (size_t)128 * 4096;
  const ushort* Bsrc0 = W + (size_t)(nl0 + srow) * K + scol;
  const ushort* Bsrc1 = Bsrc0 + (size_t)128 * K;
  const int d0 = tid * 8;          // LDS element offset, issue 0
  const int d1 = 4096 + tid * 8;   // issue 1 (rows 128..255)

  f32x4 acc[8][4];
#pragma unroll
  for (int mi = 0; mi < 8; ++mi)
#pragma unroll
    for (int ni = 0; ni < 4; ++ni)
      acc[mi][ni] = (f32x4){0.f, 0.f, 0.f, 0.f};

  // ---- prologue: stage tiles 0,1,2 into bufs 0,1,2 ----
#pragma unroll
  for (int pt = 0; pt < 3; ++pt) {
    const int ks = pt * 32;
    gload16(Asrc0 + ks, &sA[pt][d0]);
    gload16(Asrc1 + ks, &sA[pt][d1]);
    gload16(Bsrc0 + ks, &sB[pt][d0]);
    gload16(Bsrc1 + ks, &sB[pt][d1]);
  }
  asm volatile("s_waitcnt vmcnt(8)" ::: "memory");  // tile 0 landed
  __builtin_amdgcn_s_barrier();

  // ---- main loop: 1 K-tile per iteration, 2 phases ----
  for (int t = 0; t < NT; ++t) {
    const int b = t & 3;
    const ushort* pa = &sA[b][(wm * 128 + fr) * 32 + swz_e];
    const ushort* pb = &sB[b][(wn * 64 + fr) * 32 + swz_e];
    // stage tile t+3 (clamped in the tail: redundant but keeps vmcnt math)
    const int ts = (t + 3 < NT) ? (t + 3) : (NT - 1);
    const int ks = ts << 5;
    const int bs = (t + 3) & 3;

    // ---- phase A: quadrant mi 0..3 ----
    bf16x8 a0 = *(const bf16x8*)(pa);
    bf16x8 a1 = *(const bf16x8*)(pa + 512);
    bf16x8 a2 = *(const bf16x8*)(pa + 1024);
    bf16x8 a3 = *(const bf16x8*)(pa + 1536);
    bf16x8 b0 = *(const bf16x8*)(pb);
    bf16x8 b1 = *(const bf16x8*)(pb + 512);
    bf16x8 b2 = *(const bf16x8*)(pb + 1024);
    bf16x8 b3 = *(const bf16x8*)(pb + 1536);
    gload16(Asrc0 + ks, &sA[bs][d0]);
    gload16(Asrc1 + ks, &sA[bs][d1]);
    __builtin_amdgcn_s_setprio(1);
    MF(a0, b0, 0, 0); MF(a0, b1, 0, 1); MF(a0, b2, 0, 2); MF(a0, b3, 0, 3);
    MF(a1, b0, 1, 0); MF(a1, b1, 1, 1); MF(a1, b2, 1, 2); MF(a1, b3, 1, 3);
    MF(a2, b0, 2, 0); MF(a2, b1, 2, 1); MF(a2, b2, 2, 2); MF(a2, b3, 2, 3);
    MF(a3, b0, 3, 0); MF(a3, b1, 3, 1); MF(a3, b2, 3, 2); MF(a3, b3, 3, 3);
    __builtin_amdgcn_s_setprio(0);

    // ---- phase B: quadrant mi 4..7 ----
    bf16x8 a4 = *(const bf16x8*)(pa + 2048);
    bf16x8 a5 = *(const bf16x8*)(pa + 2560);
    bf16x8 a6 = *(const bf16x8*)(pa + 3072);
    bf16x8 a7 = *(const bf16x8*)(pa + 3584);
    gload16(Bsrc0 + ks, &sB[bs][d0]);
    gload16(Bsrc1 + ks, &sB[bs][d1]);
    __builtin_amdgcn_s_setprio(1);
    MF(a4, b0, 4, 0); MF(a4, b1, 4, 1); MF(a4, b2, 4, 2); MF(a4, b3, 4, 3);
    MF(a5, b0, 5, 0); MF(a5, b1, 5, 1); MF(a5, b2, 5, 2); MF(a5, b3, 5, 3);
    MF(a6, b0, 6, 0); MF(a6, b1, 6, 1); MF(a6, b2, 6, 2); MF(a6, b3, 6, 3);
    MF(a7, b0, 7, 0); MF(a7, b1, 7, 1); MF(a7, b2, 7, 2); MF(a7, b3, 7, 3);
    __builtin_amdgcn_s_setprio(0);

    // t+1's stage batch (issued during t-2) is older than the newest 8 loads
    asm volatile("s_waitcnt vmcnt(8)" ::: "memory");
    __builtin_amdgcn_s_barrier();
  }

  // ---- epilogue: C/D layout col=lane&15, row=(lane>>4)*4+reg [m89] ----
  const int rq = (lane >> 4) * 4;
#pragma unroll
  for (int mi = 0; mi < 8; ++mi) {
#pragma unroll
    for (int ni = 0; ni < 4; ++ni) {
      const int n = n0 + wn * 64 + ni * 16 + fr;
#pragma unroll
      for (int r = 0; r < 4; ++r) {
        const int m = m0 + wm * 128 + mi * 16 + rq + r;
        out[(size_t)m * 4096 + n] = acc[mi][ni][r];
      }
    }
  }
}

// Correct-but-slow fallback if workspace is too small for bf16 copies.
__global__ void naive_kernel(const float* __restrict__ x,
                             const float* __restrict__ W0,
                             const float* __restrict__ W1,
                             const float* __restrict__ W2,
                             float* __restrict__ out) {
  long idx = (long)blockIdx.x * 256 + threadIdx.x;
  int n = (int)(idx & 4095);
  long m = idx >> 12;
  int K; const float* W; int nl;
  if (n < 1024)      { K = 1024; W = W0; nl = n; }
  else if (n < 2048) { K = 2048; W = W1; nl = n - 1024; }
  else               { K = 4096; W = W2; nl = n - 2048; }
  const float* xr = x + m * 4096;
  const float* wr = W + (long)nl * K;
  float s = 0.f;
  for (int k = 0; k < K; ++k) s += xr[k] * wr[k];
  out[idx] = s;
}

extern "C" void kernel_launch(void* const* d_in, const int* in_sizes, int n_in,
                              void* d_out, int out_size, void* d_ws,
                              size_t ws_size, hipStream_t stream) {
  const float* x  = (const float*)d_in[0];
  const float* W0 = (const float*)d_in[1];
  const float* W1 = (const float*)d_in[2];
  const float* W2 = (const float*)d_in[3];
  float* out = (float*)d_out;

  const size_t xN  = (size_t)16384 * 4096;
  const size_t w0N = (size_t)1024 * 1024;
  const size_t w1N = (size_t)1024 * 2048;
  const size_t w2N = (size_t)2048 * 4096;
  const size_t need = (xN + w0N + w1N + w2N) * sizeof(ushort);  // ~150 MB

  if (ws_size >= need) {
    ushort* xbf = (ushort*)d_ws;
    ushort* w0b = xbf + xN;
    ushort* w1b = w0b + w0N;
    ushort* w2b = w1b + w1N;
    cvt_f32_bf16<<<2048, 256, 0, stream>>>(x, xbf, (int)(xN >> 2));
    cvt_f32_bf16<<<256, 256, 0, stream>>>(W0, w0b, (int)(w0N >> 2));
    cvt_f32_bf16<<<256, 256, 0, stream>>>(W1, w1b, (int)(w1N >> 2));
    cvt_f32_bf16<<<512, 256, 0, stream>>>(W2, w2b, (int)(w2N >> 2));
    // grid: 64 row-tiles (fast) x 16 col-tiles (slow)
    matry_gemm<<<1024, 512, 0, stream>>>(xbf, w0b, w1b, w2b, out);
  } else {
    naive_kernel<<<(int)((xN + 255) / 256), 256, 0, stream>>>(x, W0, W1, W2, out);
  }
}

// Round 3
// 452.189 us; speedup vs baseline: 1.5042x; 1.0237x over previous
//
#include <hip/hip_runtime.h>
#include <hip/hip_bf16.h>

// Matryoshka linear: y[m][n] = sum_k x[m][k] * W_seg[n_local][k]
//   seg0: n in [0,1024),    K=1024, W0 [1024][1024]
//   seg1: n in [1024,2048), K=2048, W1 [1024][2048]
//   seg2: n in [2048,4096), K=4096, W2 [2048][4096]
// M = 16384, out [16384][4096] fp32.
//
// Round 3: fix T2 swizzle to be conflict-free at 8-lane-group granularity.
//   quad(lane) = 4*(row&1) + slot mod 8 ; need slot = h ^ ((fr>>1)&3)
//   so every consecutive 8-lane group covers all 8 bank-quads.
// Staging inverse: LDS slot s of row r holds k-chunk s ^ ((r>>1)&3).
// Same 4-buffer pipeline, prefetch 3, counted vmcnt(8), raw s_barrier.

typedef short bf16x8 __attribute__((ext_vector_type(8)));
typedef float f32x4 __attribute__((ext_vector_type(4)));

__device__ __forceinline__ ushort f2bf(float f) {
  union { float f; unsigned u; } c; c.f = f;
  unsigned u = c.u;
  unsigned r = u + 0x7fffu + ((u >> 16) & 1u);  // RNE
  return (ushort)(r >> 16);
}

// One fused convert: dst (bf16) is contiguous in ws = [x | W0 | W1 | W2].
__global__ void cvt_all_bf16(const float* __restrict__ x,
                             const float* __restrict__ W0,
                             const float* __restrict__ W1,
                             const float* __restrict__ W2,
                             ushort* __restrict__ dst) {
  const int X4  = 16777216;             // xN/4
  const int E0  = X4 + 262144;          // + w0N/4
  const int E1  = E0 + 524288;          // + w1N/4
  const int E2  = E1 + 2097152;         // + w2N/4 (total float4 count)
  int i = blockIdx.x * blockDim.x + threadIdx.x;
  int stride = gridDim.x * blockDim.x;
  ushort4* out4 = (ushort4*)dst;
  for (int j = i; j < E2; j += stride) {
    const float4* src;
    if (j < X4)      src = (const float4*)x  + j;
    else if (j < E0) src = (const float4*)W0 + (j - X4);
    else if (j < E1) src = (const float4*)W1 + (j - E0);
    else             src = (const float4*)W2 + (j - E1);
    float4 v = *src;
    ushort4 o;
    o.x = f2bf(v.x); o.y = f2bf(v.y); o.z = f2bf(v.z); o.w = f2bf(v.w);
    out4[j] = o;
  }
}

__device__ __forceinline__ void gload16(const ushort* g, const ushort* l) {
  __builtin_amdgcn_global_load_lds(
      (const __attribute__((address_space(1))) void*)g,
      (__attribute__((address_space(3))) void*)l, 16, 0, 0);
}

#define TILE_E 8192   // one 256x32 bf16 tile = 16 KB = 8192 ushorts

#define MF(av, bv, mi, ni) \
  acc[mi][ni] = __builtin_amdgcn_mfma_f32_16x16x32_bf16(av, bv, acc[mi][ni], 0, 0, 0)

__global__ __launch_bounds__(512, 2) void matry_gemm(
    const ushort* __restrict__ xbf,   // [16384][4096] bf16
    const ushort* __restrict__ w0,    // [1024][1024]
    const ushort* __restrict__ w1,    // [1024][2048]
    const ushort* __restrict__ w2,    // [2048][4096]
    float* __restrict__ out) {        // [16384][4096] f32
  __shared__ __align__(16) ushort sA[4][TILE_E];
  __shared__ __align__(16) ushort sB[4][TILE_E];

  const int bid = blockIdx.x;
  const int rt = bid & 63;    // row tile fastest: same-rt blocks (A reuse)
  const int ct = bid >> 6;    // land on the same XCD (64 % 8 == 0)

  int K; const ushort* W; int nl0;
  if (ct < 4)      { K = 1024; W = w0; nl0 = ct * 256; }
  else if (ct < 8) { K = 2048; W = w1; nl0 = (ct - 4) * 256; }
  else             { K = 4096; W = w2; nl0 = (ct - 8) * 256; }
  const int NT = K >> 5;          // K-tiles of 32 (>=32)
  const int m0 = rt * 256;
  const int n0 = ct * 256;

  const int tid  = threadIdx.x;
  const int wid  = tid >> 6;
  const int lane = tid & 63;
  const int wm = wid >> 2;        // 0..1  (row half)
  const int wn = wid & 3;         // 0..3  (col quarter)
  const int fr = lane & 15;
  // conflict-free slot: quad = 4*(fr&1) + (h ^ ((fr>>1)&3)) covers all 8
  // bank-quads in every consecutive 8-lane group.
  const int swz_e = (((lane >> 4) ^ ((lane >> 1) & 3)) << 3);

  // ---- staging (pre-swizzled global source, linear LDS dest) ----
  // LDS slot s of row r must hold k-chunk  s ^ ((r>>1)&3).
  // thread tid writes LDS element tid*8 (+issue*4096): row = tid>>2 (+128*is),
  // slot = tid&3  ->  source chunk = (tid&3) ^ ((tid>>3)&3)
  const int srow = tid >> 2;                                   // 0..127
  const int scol = (((tid & 3) ^ ((tid >> 3) & 3)) << 3);      // elements
  const ushort* Asrc0 = xbf + (size_t)(m0 + srow) * 4096 + scol;
  const ushort* Asrc1 = Asrc0 + (size_t)128 * 4096;
  const ushort* Bsrc0 = W + (size_t)(nl0 + srow) * K + scol;
  const ushort* Bsrc1 = Bsrc0 + (size_t)128 * K;
  const int d0 = tid * 8;          // LDS element offset, issue 0
  const int d1 = 4096 + tid * 8;   // issue 1 (rows 128..255)

  f32x4 acc[8][4];
#pragma unroll
  for (int mi = 0; mi < 8; ++mi)
#pragma unroll
    for (int ni = 0; ni < 4; ++ni)
      acc[mi][ni] = (f32x4){0.f, 0.f, 0.f, 0.f};

  // ---- prologue: stage tiles 0,1,2 into bufs 0,1,2 ----
#pragma unroll
  for (int pt = 0; pt < 3; ++pt) {
    const int ks = pt * 32;
    gload16(Asrc0 + ks, &sA[pt][d0]);
    gload16(Asrc1 + ks, &sA[pt][d1]);
    gload16(Bsrc0 + ks, &sB[pt][d0]);
    gload16(Bsrc1 + ks, &sB[pt][d1]);
  }
  asm volatile("s_waitcnt vmcnt(8)" ::: "memory");  // tile 0 landed
  __builtin_amdgcn_s_barrier();

  // ---- main loop: 1 K-tile per iteration, 2 MFMA phases ----
  for (int t = 0; t < NT; ++t) {
    const int b = t & 3;
    const ushort* pa = &sA[b][(wm * 128 + fr) * 32 + swz_e];
    const ushort* pb = &sB[b][(wn * 64 + fr) * 32 + swz_e];
    // stage tile t+3 (clamped in the tail: redundant but keeps vmcnt math)
    const int ts = (t + 3 < NT) ? (t + 3) : (NT - 1);
    const int ks = ts << 5;
    const int bs = (t + 3) & 3;

    // ---- phase A: quadrant mi 0..3 ----
    bf16x8 a0 = *(const bf16x8*)(pa);
    bf16x8 a1 = *(const bf16x8*)(pa + 512);
    bf16x8 a2 = *(const bf16x8*)(pa + 1024);
    bf16x8 a3 = *(const bf16x8*)(pa + 1536);
    bf16x8 b0 = *(const bf16x8*)(pb);
    bf16x8 b1 = *(const bf16x8*)(pb + 512);
    bf16x8 b2 = *(const bf16x8*)(pb + 1024);
    bf16x8 b3 = *(const bf16x8*)(pb + 1536);
    gload16(Asrc0 + ks, &sA[bs][d0]);
    gload16(Asrc1 + ks, &sA[bs][d1]);
    __builtin_amdgcn_s_setprio(1);
    MF(a0, b0, 0, 0); MF(a0, b1, 0, 1); MF(a0, b2, 0, 2); MF(a0, b3, 0, 3);
    MF(a1, b0, 1, 0); MF(a1, b1, 1, 1); MF(a1, b2, 1, 2); MF(a1, b3, 1, 3);
    MF(a2, b0, 2, 0); MF(a2, b1, 2, 1); MF(a2, b2, 2, 2); MF(a2, b3, 2, 3);
    MF(a3, b0, 3, 0); MF(a3, b1, 3, 1); MF(a3, b2, 3, 2); MF(a3, b3, 3, 3);
    __builtin_amdgcn_s_setprio(0);

    // ---- phase B: quadrant mi 4..7 ----
    bf16x8 a4 = *(const bf16x8*)(pa + 2048);
    bf16x8 a5 = *(const bf16x8*)(pa + 2560);
    bf16x8 a6 = *(const bf16x8*)(pa + 3072);
    bf16x8 a7 = *(const bf16x8*)(pa + 3584);
    gload16(Bsrc0 + ks, &sB[bs][d0]);
    gload16(Bsrc1 + ks, &sB[bs][d1]);
    __builtin_amdgcn_s_setprio(1);
    MF(a4, b0, 4, 0); MF(a4, b1, 4, 1); MF(a4, b2, 4, 2); MF(a4, b3, 4, 3);
    MF(a5, b0, 5, 0); MF(a5, b1, 5, 1); MF(a5, b2, 5, 2); MF(a5, b3, 5, 3);
    MF(a6, b0, 6, 0); MF(a6, b1, 6, 1); MF(a6, b2, 6, 2); MF(a6, b3, 6, 3);
    MF(a7, b0, 7, 0); MF(a7, b1, 7, 1); MF(a7, b2, 7, 2); MF(a7, b3, 7, 3);
    __builtin_amdgcn_s_setprio(0);

    // tile t+1's 4 loads (issued at iter t-2) are the oldest of 12 in flight
    asm volatile("s_waitcnt vmcnt(8)" ::: "memory");
    __builtin_amdgcn_s_barrier();
  }

  // ---- epilogue: C/D layout col=lane&15, row=(lane>>4)*4+reg [m89] ----
  const int rq = (lane >> 4) * 4;
#pragma unroll
  for (int mi = 0; mi < 8; ++mi) {
#pragma unroll
    for (int ni = 0; ni < 4; ++ni) {
      const int n = n0 + wn * 64 + ni * 16 + fr;
#pragma unroll
      for (int r = 0; r < 4; ++r) {
        const int m = m0 + wm * 128 + mi * 16 + rq + r;
        out[(size_t)m * 4096 + n] = acc[mi][ni][r];
      }
    }
  }
}

// Correct-but-slow fallback if workspace is too small for bf16 copies.
__global__ void naive_kernel(const float* __restrict__ x,
                             const float* __restrict__ W0,
                             const float* __restrict__ W1,
                             const float* __restrict__ W2,
                             float* __restrict__ out) {
  long idx = (long)blockIdx.x * 256 + threadIdx.x;
  int n = (int)(idx & 4095);
  long m = idx >> 12;
  int K; const float* W; int nl;
  if (n < 1024)      { K = 1024; W = W0; nl = n; }
  else if (n < 2048) { K = 2048; W = W1; nl = n - 1024; }
  else               { K = 4096; W = W2; nl = n - 2048; }
  const float* xr = x + m * 4096;
  const float* wr = W + (long)nl * K;
  float s = 0.f;
  for (int k = 0; k < K; ++k) s += xr[k] * wr[k];
  out[idx] = s;
}

extern "C" void kernel_launch(void* const* d_in, const int* in_sizes, int n_in,
                              void* d_out, int out_size, void* d_ws,
                              size_t ws_size, hipStream_t stream) {
  const float* x  = (const float*)d_in[0];
  const float* W0 = (const float*)d_in[1];
  const float* W1 = (const float*)d_in[2];
  const float* W2 = (const float*)d_in[3];
  float* out = (float*)d_out;

  const size_t xN  = (size_t)16384 * 4096;
  const size_t w0N = (size_t)1024 * 1024;
  const size_t w1N = (size_t)1024 * 2048;
  const size_t w2N = (size_t)2048 * 4096;
  const size_t need = (xN + w0N + w1N + w2N) * sizeof(ushort);  // ~150 MB

  if (ws_size >= need) {
    ushort* xbf = (ushort*)d_ws;
    ushort* w0b = xbf + xN;
    ushort* w1b = w0b + w0N;
    ushort* w2b = w1b + w1N;
    cvt_all_bf16<<<4096, 256, 0, stream>>>(x, W0, W1, W2, xbf);
    // grid: 64 row-tiles (fast) x 16 col-tiles (slow)
    matry_gemm<<<1024, 512, 0, stream>>>(xbf, w0b, w1b, w2b, out);
  } else {
    naive_kernel<<<(int)((xN + 255) / 256), 256, 0, stream>>>(x, W0, W1, W2, out);
  }
}